// Round 5
// baseline (553.263 us; speedup 1.0000x reference)
//
#include <hip/hip_runtime.h>
#include <math.h>

#define D_MODEL 512
#define HEAD_DIM 64
#define NUM_HEADS 8
#define SEQ 2048
#define BATCH 4
#define ROWS (BATCH * SEQ)  // 8192
#define PLANE ((size_t)ROWS * D_MODEL)  // 4194304 elems

typedef short v8s __attribute__((ext_vector_type(8)));
typedef float v4f __attribute__((ext_vector_type(4)));

#define MFMA16(a, b, c) __builtin_amdgcn_mfma_f32_16x16x32_bf16(a, b, c, 0, 0, 0)

__device__ __forceinline__ unsigned short bf16_rne(float x) {
  unsigned u = __float_as_uint(x);
  u += 0x7fffu + ((u >> 16) & 1u);
  return (unsigned short)(u >> 16);
}
__device__ __forceinline__ float bf16f(unsigned short h) {
  return __uint_as_float(((unsigned)h) << 16);
}

// ---------------------------------------------------------------------------
// MFMA projection (validated r4, ~135us with vtrans): y = x @ W^T + b via
// 3-term bf16 hi/lo split. z==0 pre-scaled by 0.125; z==2 -> bf16 V plane.
// ---------------------------------------------------------------------------
__global__ __launch_bounds__(256) void proj_mfma_kernel(
    const float* __restrict__ q, const float* __restrict__ k,
    const float* __restrict__ v, const float* __restrict__ Wq,
    const float* __restrict__ bq, const float* __restrict__ Wk,
    const float* __restrict__ bk, const float* __restrict__ Wv,
    const float* __restrict__ bv, unsigned short* __restrict__ q_hi,
    unsigned short* __restrict__ q_lo, unsigned short* __restrict__ k_hi,
    unsigned short* __restrict__ k_lo, unsigned short* __restrict__ v_b) {
  const int z = blockIdx.z;
  const float* x;
  const float* W;
  const float* bias;
  if (z == 0) {
    x = q; W = Wq; bias = bq;
  } else if (z == 1) {
    x = k; W = Wk; bias = bk;
  } else {
    x = v; W = Wv; bias = bv;
  }

  __shared__ unsigned short Xh[64][40];
  __shared__ unsigned short Xl[64][40];
  __shared__ unsigned short Wh[256][40];
  __shared__ unsigned short Wl[256][40];

  const int tid = threadIdx.x;
  const int w = tid >> 6;
  const int lane = tid & 63;
  const int g = lane >> 4;
  const int c = lane & 15;
  const int m0 = blockIdx.x * 64;
  const int n0 = blockIdx.y * 256;

  v4f acc[16];
#pragma unroll
  for (int i = 0; i < 16; ++i) acc[i] = (v4f){0.f, 0.f, 0.f, 0.f};

  const int xr = tid >> 2;       // staging row 0..63
  const int xs = (tid & 3) * 8;  // k offset 0,8,16,24

  for (int k0 = 0; k0 < D_MODEL; k0 += 32) {
    float xv[8];
    *reinterpret_cast<float4*>(&xv[0]) = *reinterpret_cast<const float4*>(
        &x[(size_t)(m0 + xr) * D_MODEL + k0 + xs]);
    *reinterpret_cast<float4*>(&xv[4]) = *reinterpret_cast<const float4*>(
        &x[(size_t)(m0 + xr) * D_MODEL + k0 + xs + 4]);
    float wv[4][8];
#pragma unroll
    for (int i = 0; i < 4; ++i) {
      *reinterpret_cast<float4*>(&wv[i][0]) = *reinterpret_cast<const float4*>(
          &W[(size_t)(n0 + xr + 64 * i) * D_MODEL + k0 + xs]);
      *reinterpret_cast<float4*>(&wv[i][4]) = *reinterpret_cast<const float4*>(
          &W[(size_t)(n0 + xr + 64 * i) * D_MODEL + k0 + xs + 4]);
    }
    __syncthreads();
    {
      unsigned short h8[8], l8[8];
#pragma unroll
      for (int j = 0; j < 8; ++j) {
        h8[j] = bf16_rne(xv[j]);
        l8[j] = bf16_rne(xv[j] - bf16f(h8[j]));
      }
      *reinterpret_cast<uint4*>(&Xh[xr][xs]) = *reinterpret_cast<uint4*>(&h8[0]);
      *reinterpret_cast<uint4*>(&Xl[xr][xs]) = *reinterpret_cast<uint4*>(&l8[0]);
#pragma unroll
      for (int i = 0; i < 4; ++i) {
#pragma unroll
        for (int j = 0; j < 8; ++j) {
          h8[j] = bf16_rne(wv[i][j]);
          l8[j] = bf16_rne(wv[i][j] - bf16f(h8[j]));
        }
        *reinterpret_cast<uint4*>(&Wh[xr + 64 * i][xs]) =
            *reinterpret_cast<uint4*>(&h8[0]);
        *reinterpret_cast<uint4*>(&Wl[xr + 64 * i][xs]) =
            *reinterpret_cast<uint4*>(&l8[0]);
      }
    }
    __syncthreads();

    const v8s ah = *reinterpret_cast<const v8s*>(&Xh[w * 16 + c][g * 8]);
    const v8s al = *reinterpret_cast<const v8s*>(&Xl[w * 16 + c][g * 8]);
#pragma unroll
    for (int nt = 0; nt < 16; ++nt) {
      const v8s bh = *reinterpret_cast<const v8s*>(&Wh[nt * 16 + c][g * 8]);
      const v8s bl = *reinterpret_cast<const v8s*>(&Wl[nt * 16 + c][g * 8]);
      acc[nt] = MFMA16(ah, bh, acc[nt]);
      acc[nt] = MFMA16(ah, bl, acc[nt]);
      acc[nt] = MFMA16(al, bh, acc[nt]);
    }
  }

  if (z < 2) {
    unsigned short* hp = (z == 0) ? q_hi : k_hi;
    unsigned short* lp = (z == 0) ? q_lo : k_lo;
    const float sc = (z == 0) ? 0.125f : 1.0f;
#pragma unroll
    for (int nt = 0; nt < 16; ++nt) {
      const float bb = bias[n0 + nt * 16 + c];
#pragma unroll
      for (int r = 0; r < 4; ++r) {
        const float y = (acc[nt][r] + bb) * sc;
        const unsigned short hb = bf16_rne(y);
        const unsigned short lb = bf16_rne(y - bf16f(hb));
        const size_t off =
            (size_t)(m0 + w * 16 + g * 4 + r) * D_MODEL + n0 + nt * 16 + c;
        hp[off] = hb;
        lp[off] = lb;
      }
    }
  } else {
#pragma unroll
    for (int nt = 0; nt < 16; ++nt) {
      const float bb = bias[n0 + nt * 16 + c];
#pragma unroll
      for (int r = 0; r < 4; ++r) {
        const size_t off =
            (size_t)(m0 + w * 16 + g * 4 + r) * D_MODEL + n0 + nt * 16 + c;
        v_b[off] = bf16_rne(acc[nt][r] + bb);
      }
    }
  }
}

// ---------------------------------------------------------------------------
// V transpose: v_b [b*2048+kpos][512] -> vt [b*512+col][2048] (bf16).
// ---------------------------------------------------------------------------
__global__ __launch_bounds__(256) void vtrans_kernel(
    const unsigned short* __restrict__ vb, unsigned short* __restrict__ vt) {
  __shared__ unsigned short T[64][72];
  const int kt = blockIdx.x, ct = blockIdx.y, b = blockIdx.z;
  const int t = threadIdx.x;
  const int r = t >> 3, seg = t & 7;
#pragma unroll
  for (int i = 0; i < 2; ++i) {
    const int row = r + 32 * i;
    const uint4 val = *reinterpret_cast<const uint4*>(
        &vb[((size_t)(b * 2048 + kt * 64 + row)) * 512 + ct * 64 + seg * 8]);
    *reinterpret_cast<uint4*>(&T[row][seg * 8]) = val;
  }
  __syncthreads();
#pragma unroll
  for (int i = 0; i < 2; ++i) {
    const int col = r + 32 * i;
    unsigned short tmp[8];
#pragma unroll
    for (int j = 0; j < 8; ++j) tmp[j] = T[seg * 8 + j][col];
    *reinterpret_cast<uint4*>(
        &vt[((size_t)(b * 512 + ct * 64 + col)) * 2048 + kt * 64 + seg * 8]) =
        *reinterpret_cast<uint4*>(&tmp[0]);
  }
}

// ---------------------------------------------------------------------------
// Flash attention, bf16 MFMA, fp32-grade. 4 waves x 16 q-rows = 64 q-rows
// per block, BK=64, grid 1024. r4's spill root-caused: two-pass PV kept s[]
// live across PV pass 1 under a 128-VGPR cap -> per-iteration scratch
// (783MB WRITE_SIZE). Fix: r3-proven single-pass packed-u32 P (hi|lo<<16,
// s[] dies at pack), one PV phase doing hi+lo MFMAs. LDS 45KB -> 3
// blocks/CU (12 waves, 1.5x r3). Peak live regs ~119 < 128: no spill.
// ---------------------------------------------------------------------------
__global__ __launch_bounds__(256, 4) void mha_attn_mfma(
    const unsigned short* __restrict__ qhi, const unsigned short* __restrict__ qlo,
    const unsigned short* __restrict__ khi, const unsigned short* __restrict__ klo,
    const unsigned short* __restrict__ vt, float* __restrict__ out) {
  __shared__ unsigned short Khs[64][72];
  __shared__ unsigned short Kls[64][72];
  __shared__ unsigned short Vts[64][72];
  __shared__ unsigned Pl[4][16][68];  // per-wave packed P (hi|lo<<16)

  const int tid = threadIdx.x;
  const int w = tid >> 6;
  const int lane = tid & 63;
  const int g = lane >> 4;
  const int c = lane & 15;
  const int bid = blockIdx.x;
  const int qt = bid & 31;
  const int h = (bid >> 5) & 7;
  const int b = bid >> 8;
  const int q0 = qt * 64 + w * 16;

  v8s qfh[2], qfl[2];
#pragma unroll
  for (int kh = 0; kh < 2; ++kh) {
    const size_t off =
        ((size_t)(b * 2048 + q0 + c)) * 512 + h * 64 + kh * 32 + g * 8;
    qfh[kh] = *reinterpret_cast<const v8s*>(&qhi[off]);
    qfl[kh] = *reinterpret_cast<const v8s*>(&qlo[off]);
  }

  v4f ctx[4];
#pragma unroll
  for (int dt = 0; dt < 4; ++dt) ctx[dt] = (v4f){0.f, 0.f, 0.f, 0.f};
  float mrun[4], lrun[4];
#pragma unroll
  for (int r = 0; r < 4; ++r) {
    mrun[r] = -1.0e30f;
    lrun[r] = 0.f;
  }

  const int srow = tid >> 3;  // 0..31
  const int sseg = tid & 7;   // 0..7

  for (int kt = 0; kt < SEQ / 64; ++kt) {
    uint4 sk[2], sl[2], sv[2];
#pragma unroll
    for (int i = 0; i < 2; ++i) {
      const int r = srow + 32 * i;
      const size_t ka =
          ((size_t)(b * 2048 + kt * 64 + r)) * 512 + h * 64 + sseg * 8;
      sk[i] = *reinterpret_cast<const uint4*>(&khi[ka]);
      sl[i] = *reinterpret_cast<const uint4*>(&klo[ka]);
      const size_t va =
          ((size_t)(b * 512 + h * 64 + r)) * 2048 + kt * 64 + sseg * 8;
      sv[i] = *reinterpret_cast<const uint4*>(&vt[va]);
    }
    __syncthreads();
#pragma unroll
    for (int i = 0; i < 2; ++i) {
      const int r = srow + 32 * i;
      *reinterpret_cast<uint4*>(&Khs[r][sseg * 8]) = sk[i];
      *reinterpret_cast<uint4*>(&Kls[r][sseg * 8]) = sl[i];
      *reinterpret_cast<uint4*>(&Vts[r][sseg * 8]) = sv[i];
    }
    __syncthreads();

    // ---- QK^T: 3-term split, 24 MFMAs (Q pre-scaled by 1/8) ----
    v4f s[4];
#pragma unroll
    for (int ct = 0; ct < 4; ++ct) s[ct] = (v4f){0.f, 0.f, 0.f, 0.f};
#pragma unroll
    for (int kh = 0; kh < 2; ++kh)
#pragma unroll
      for (int ct = 0; ct < 4; ++ct) {
        const v8s bh =
            *reinterpret_cast<const v8s*>(&Khs[ct * 16 + c][kh * 32 + g * 8]);
        const v8s bl =
            *reinterpret_cast<const v8s*>(&Kls[ct * 16 + c][kh * 32 + g * 8]);
        s[ct] = MFMA16(qfh[kh], bh, s[ct]);
        s[ct] = MFMA16(qfh[kh], bl, s[ct]);
        s[ct] = MFMA16(qfl[kh], bh, s[ct]);
      }

    // ---- online softmax (rows r = g*4+r across 16 c-lanes) ----
    float al[4];
#pragma unroll
    for (int r = 0; r < 4; ++r) {
      float mx = fmaxf(fmaxf(s[0][r], s[1][r]), fmaxf(s[2][r], s[3][r]));
      mx = fmaxf(mx, __shfl_xor(mx, 1, 16));
      mx = fmaxf(mx, __shfl_xor(mx, 2, 16));
      mx = fmaxf(mx, __shfl_xor(mx, 4, 16));
      mx = fmaxf(mx, __shfl_xor(mx, 8, 16));
      const float mn = fmaxf(mrun[r], mx);
      al[r] = __expf(mrun[r] - mn);
      mrun[r] = mn;
    }
#pragma unroll
    for (int ct = 0; ct < 4; ++ct)
#pragma unroll
      for (int r = 0; r < 4; ++r) s[ct][r] = __expf(s[ct][r] - mrun[r]);
#pragma unroll
    for (int r = 0; r < 4; ++r) {
      float ps = s[0][r] + s[1][r] + s[2][r] + s[3][r];
      ps += __shfl_xor(ps, 1, 16);
      ps += __shfl_xor(ps, 2, 16);
      ps += __shfl_xor(ps, 4, 16);
      ps += __shfl_xor(ps, 8, 16);
      lrun[r] = lrun[r] * al[r] + ps;
    }
#pragma unroll
    for (int dt = 0; dt < 4; ++dt)
#pragma unroll
      for (int r = 0; r < 4; ++r) ctx[dt][r] *= al[r];

    // ---- pack P hi|lo into one u32 plane (s dies here) ----
#pragma unroll
    for (int ct = 0; ct < 4; ++ct)
#pragma unroll
      for (int r = 0; r < 4; ++r) {
        const float p = s[ct][r];
        const unsigned u = __float_as_uint(p);
        const unsigned hi = u >> 16;
        const float lof = p - __uint_as_float(u & 0xffff0000u);
        const unsigned lo = __float_as_uint(lof) >> 16;
        Pl[w][g * 4 + r][ct * 16 + c] = hi | (lo << 16);
      }

    // ---- PV: single pass, hi+lo MFMAs (same-wave DS RAW, no barrier) ----
#pragma unroll
    for (int kh = 0; kh < 2; ++kh) {
      const uint4 a0 =
          *reinterpret_cast<const uint4*>(&Pl[w][c][kh * 32 + g * 8]);
      const uint4 a1 =
          *reinterpret_cast<const uint4*>(&Pl[w][c][kh * 32 + g * 8 + 4]);
      uint4 hh, ll;
      hh.x = (a0.x & 0xffffu) | (a0.y << 16);
      hh.y = (a0.z & 0xffffu) | (a0.w << 16);
      hh.z = (a1.x & 0xffffu) | (a1.y << 16);
      hh.w = (a1.z & 0xffffu) | (a1.w << 16);
      ll.x = (a0.x >> 16) | (a0.y & 0xffff0000u);
      ll.y = (a0.z >> 16) | (a0.w & 0xffff0000u);
      ll.z = (a1.x >> 16) | (a1.y & 0xffff0000u);
      ll.w = (a1.z >> 16) | (a1.w & 0xffff0000u);
      const v8s pah = __builtin_bit_cast(v8s, hh);
      const v8s pal = __builtin_bit_cast(v8s, ll);
#pragma unroll
      for (int dt = 0; dt < 4; ++dt) {
        const v8s vb =
            *reinterpret_cast<const v8s*>(&Vts[dt * 16 + c][kh * 32 + g * 8]);
        ctx[dt] = MFMA16(pah, vb, ctx[dt]);
        ctx[dt] = MFMA16(pal, vb, ctx[dt]);
      }
    }
  }

  float inv[4];
#pragma unroll
  for (int r = 0; r < 4; ++r) inv[r] = 1.0f / lrun[r];
#pragma unroll
  for (int dt = 0; dt < 4; ++dt)
#pragma unroll
    for (int r = 0; r < 4; ++r)
      out[((size_t)(b * 2048 + q0 + g * 4 + r)) * 512 + h * 64 + dt * 16 + c] =
          ctx[dt][r] * inv[r];
}

extern "C" void kernel_launch(void* const* d_in, const int* in_sizes, int n_in,
                              void* d_out, int out_size, void* d_ws,
                              size_t ws_size, hipStream_t stream) {
  const float* q = (const float*)d_in[0];
  const float* k = (const float*)d_in[1];
  const float* v = (const float*)d_in[2];
  const float* Wq_w = (const float*)d_in[3];
  const float* Wq_b = (const float*)d_in[4];
  const float* Wk_w = (const float*)d_in[5];
  const float* Wk_b = (const float*)d_in[6];
  const float* Wv_w = (const float*)d_in[7];
  const float* Wv_b = (const float*)d_in[8];
  float* out = (float*)d_out;

  unsigned short* q_hi = (unsigned short*)d_ws;
  unsigned short* q_lo = q_hi + PLANE;
  unsigned short* k_hi = q_lo + PLANE;
  unsigned short* k_lo = k_hi + PLANE;
  unsigned short* v_b = k_lo + PLANE;
  unsigned short* vt = v_b + PLANE;  // 6 planes * 8 MiB = 48 MiB

  dim3 pgrid(ROWS / 64, D_MODEL / 256, 3);
  proj_mfma_kernel<<<pgrid, 256, 0, stream>>>(q, k, v, Wq_w, Wq_b, Wk_w, Wk_b,
                                              Wv_w, Wv_b, q_hi, q_lo, k_hi,
                                              k_lo, v_b);

  dim3 tgrid(SEQ / 64, D_MODEL / 64, BATCH);
  vtrans_kernel<<<tgrid, 256, 0, stream>>>(v_b, vt);

  dim3 agrid(BATCH * NUM_HEADS * (SEQ / 64));
  mha_attn_mfma<<<agrid, 256, 0, stream>>>(q_hi, q_lo, k_hi, k_lo, vt, out);
}

// Round 6
// 314.213 us; speedup vs baseline: 1.7608x; 1.7608x over previous
//
#include <hip/hip_runtime.h>
#include <math.h>

#define D_MODEL 512
#define HEAD_DIM 64
#define NUM_HEADS 8
#define SEQ 2048
#define BATCH 4
#define ROWS (BATCH * SEQ)  // 8192
#define PLANE ((size_t)ROWS * D_MODEL)  // 4194304 elems
#define NT (SEQ / 64)

typedef short v8s __attribute__((ext_vector_type(8)));
typedef float v4f __attribute__((ext_vector_type(4)));

#define MFMA16(a, b, c) __builtin_amdgcn_mfma_f32_16x16x32_bf16(a, b, c, 0, 0, 0)

__device__ __forceinline__ unsigned short bf16_rne(float x) {
  unsigned u = __float_as_uint(x);
  u += 0x7fffu + ((u >> 16) & 1u);
  return (unsigned short)(u >> 16);
}
__device__ __forceinline__ float bf16f(unsigned short h) {
  return __uint_as_float(((unsigned)h) << 16);
}

// ---------------------------------------------------------------------------
// MFMA projection (validated r4/r5): y = x @ W^T + b via 3-term bf16 hi/lo
// split. z==0 pre-scaled by 0.125; z==2 -> bf16 V plane.
// ---------------------------------------------------------------------------
__global__ __launch_bounds__(256) void proj_mfma_kernel(
    const float* __restrict__ q, const float* __restrict__ k,
    const float* __restrict__ v, const float* __restrict__ Wq,
    const float* __restrict__ bq, const float* __restrict__ Wk,
    const float* __restrict__ bk, const float* __restrict__ Wv,
    const float* __restrict__ bv, unsigned short* __restrict__ q_hi,
    unsigned short* __restrict__ q_lo, unsigned short* __restrict__ k_hi,
    unsigned short* __restrict__ k_lo, unsigned short* __restrict__ v_b) {
  const int z = blockIdx.z;
  const float* x;
  const float* W;
  const float* bias;
  if (z == 0) {
    x = q; W = Wq; bias = bq;
  } else if (z == 1) {
    x = k; W = Wk; bias = bk;
  } else {
    x = v; W = Wv; bias = bv;
  }

  __shared__ unsigned short Xh[64][40];
  __shared__ unsigned short Xl[64][40];
  __shared__ unsigned short Wh[256][40];
  __shared__ unsigned short Wl[256][40];

  const int tid = threadIdx.x;
  const int w = tid >> 6;
  const int lane = tid & 63;
  const int g = lane >> 4;
  const int c = lane & 15;
  const int m0 = blockIdx.x * 64;
  const int n0 = blockIdx.y * 256;

  v4f acc[16];
#pragma unroll
  for (int i = 0; i < 16; ++i) acc[i] = (v4f){0.f, 0.f, 0.f, 0.f};

  const int xr = tid >> 2;       // staging row 0..63
  const int xs = (tid & 3) * 8;  // k offset 0,8,16,24

  for (int k0 = 0; k0 < D_MODEL; k0 += 32) {
    float xv[8];
    *reinterpret_cast<float4*>(&xv[0]) = *reinterpret_cast<const float4*>(
        &x[(size_t)(m0 + xr) * D_MODEL + k0 + xs]);
    *reinterpret_cast<float4*>(&xv[4]) = *reinterpret_cast<const float4*>(
        &x[(size_t)(m0 + xr) * D_MODEL + k0 + xs + 4]);
    float wv[4][8];
#pragma unroll
    for (int i = 0; i < 4; ++i) {
      *reinterpret_cast<float4*>(&wv[i][0]) = *reinterpret_cast<const float4*>(
          &W[(size_t)(n0 + xr + 64 * i) * D_MODEL + k0 + xs]);
      *reinterpret_cast<float4*>(&wv[i][4]) = *reinterpret_cast<const float4*>(
          &W[(size_t)(n0 + xr + 64 * i) * D_MODEL + k0 + xs + 4]);
    }
    __syncthreads();
    {
      unsigned short h8[8], l8[8];
#pragma unroll
      for (int j = 0; j < 8; ++j) {
        h8[j] = bf16_rne(xv[j]);
        l8[j] = bf16_rne(xv[j] - bf16f(h8[j]));
      }
      *reinterpret_cast<uint4*>(&Xh[xr][xs]) = *reinterpret_cast<uint4*>(&h8[0]);
      *reinterpret_cast<uint4*>(&Xl[xr][xs]) = *reinterpret_cast<uint4*>(&l8[0]);
#pragma unroll
      for (int i = 0; i < 4; ++i) {
#pragma unroll
        for (int j = 0; j < 8; ++j) {
          h8[j] = bf16_rne(wv[i][j]);
          l8[j] = bf16_rne(wv[i][j] - bf16f(h8[j]));
        }
        *reinterpret_cast<uint4*>(&Wh[xr + 64 * i][xs]) =
            *reinterpret_cast<uint4*>(&h8[0]);
        *reinterpret_cast<uint4*>(&Wl[xr + 64 * i][xs]) =
            *reinterpret_cast<uint4*>(&l8[0]);
      }
    }
    __syncthreads();

    const v8s ah = *reinterpret_cast<const v8s*>(&Xh[w * 16 + c][g * 8]);
    const v8s al = *reinterpret_cast<const v8s*>(&Xl[w * 16 + c][g * 8]);
#pragma unroll
    for (int nt = 0; nt < 16; ++nt) {
      const v8s bh = *reinterpret_cast<const v8s*>(&Wh[nt * 16 + c][g * 8]);
      const v8s bl = *reinterpret_cast<const v8s*>(&Wl[nt * 16 + c][g * 8]);
      acc[nt] = MFMA16(ah, bh, acc[nt]);
      acc[nt] = MFMA16(ah, bl, acc[nt]);
      acc[nt] = MFMA16(al, bh, acc[nt]);
    }
  }

  if (z < 2) {
    unsigned short* hp = (z == 0) ? q_hi : k_hi;
    unsigned short* lp = (z == 0) ? q_lo : k_lo;
    const float sc = (z == 0) ? 0.125f : 1.0f;
#pragma unroll
    for (int nt = 0; nt < 16; ++nt) {
      const float bb = bias[n0 + nt * 16 + c];
#pragma unroll
      for (int r = 0; r < 4; ++r) {
        const float y = (acc[nt][r] + bb) * sc;
        const unsigned short hb = bf16_rne(y);
        const unsigned short lb = bf16_rne(y - bf16f(hb));
        const size_t off =
            (size_t)(m0 + w * 16 + g * 4 + r) * D_MODEL + n0 + nt * 16 + c;
        hp[off] = hb;
        lp[off] = lb;
      }
    }
  } else {
#pragma unroll
    for (int nt = 0; nt < 16; ++nt) {
      const float bb = bias[n0 + nt * 16 + c];
#pragma unroll
      for (int r = 0; r < 4; ++r) {
        const size_t off =
            (size_t)(m0 + w * 16 + g * 4 + r) * D_MODEL + n0 + nt * 16 + c;
        v_b[off] = bf16_rne(acc[nt][r] + bb);
      }
    }
  }
}

// ---------------------------------------------------------------------------
// V transpose: v_b [b*2048+kpos][512] -> vt [b*512+col][2048] (bf16).
// ---------------------------------------------------------------------------
__global__ __launch_bounds__(256) void vtrans_kernel(
    const unsigned short* __restrict__ vb, unsigned short* __restrict__ vt) {
  __shared__ unsigned short T[64][72];
  const int kt = blockIdx.x, ct = blockIdx.y, b = blockIdx.z;
  const int t = threadIdx.x;
  const int r = t >> 3, seg = t & 7;
#pragma unroll
  for (int i = 0; i < 2; ++i) {
    const int row = r + 32 * i;
    const uint4 val = *reinterpret_cast<const uint4*>(
        &vb[((size_t)(b * 2048 + kt * 64 + row)) * 512 + ct * 64 + seg * 8]);
    *reinterpret_cast<uint4*>(&T[row][seg * 8]) = val;
  }
  __syncthreads();
#pragma unroll
  for (int i = 0; i < 2; ++i) {
    const int col = r + 32 * i;
    unsigned short tmp[8];
#pragma unroll
    for (int j = 0; j < 8; ++j) tmp[j] = T[seg * 8 + j][col];
    *reinterpret_cast<uint4*>(
        &vt[((size_t)(b * 512 + ct * 64 + col)) * 2048 + kt * 64 + seg * 8]) =
        *reinterpret_cast<uint4*>(&tmp[0]);
  }
}

// ---------------------------------------------------------------------------
// Flash attention, bf16 MFMA, fp32-grade. r3-proven shape: 4 waves x 32
// q-rows (qt=2), grid 512, launch_bounds(256,2) -- the only non-spilling
// config (r4/r5: any >=4-waves/EU cap spills ~0.2-0.8GB/dispatch).
// New vs r3: (1) T14 prefetch -- next tile's global loads issue BEFORE
// compute so L2/HBM latency hides under 80 MFMAs (r3 stalled 14.3K cyc/iter
// vs 3.4K busy with loads exposed at the barrier); (2) slim packed-u32 P
// plane (hi|lo<<16, single-pass PV, 62.5KB LDS total, 2 blocks/CU);
// (3) P-plane XOR swizzle col^=((row>>2&3)<<2): scatter-writes drop from
// 4-way to 2-way (free), reads stay uniform (enumerated).
// ---------------------------------------------------------------------------
__global__ __launch_bounds__(256, 2) void mha_attn_mfma(
    const unsigned short* __restrict__ qhi, const unsigned short* __restrict__ qlo,
    const unsigned short* __restrict__ khi, const unsigned short* __restrict__ klo,
    const unsigned short* __restrict__ vt, float* __restrict__ out) {
  __shared__ unsigned short Khs[64][72];
  __shared__ unsigned short Kls[64][72];
  __shared__ unsigned short Vts[64][72];
  __shared__ unsigned Pl[4][32][68];  // per-wave packed P (hi|lo<<16), swizzled

  const int tid = threadIdx.x;
  const int w = tid >> 6;
  const int lane = tid & 63;
  const int g = lane >> 4;
  const int c = lane & 15;
  const int bid = blockIdx.x;
  const int qb = bid & 15;        // q-block 0..15 (128 rows)
  const int h = (bid >> 4) & 7;   // head
  const int b = bid >> 7;         // batch
  const int q0 = qb * 128 + w * 32;

  // Q fragments (hi/lo), loaded once from global (Q pre-scaled by 1/8).
  v8s qfh[2][2], qfl[2][2];
#pragma unroll
  for (int qt = 0; qt < 2; ++qt)
#pragma unroll
    for (int kh = 0; kh < 2; ++kh) {
      const size_t off = ((size_t)(b * 2048 + q0 + qt * 16 + c)) * 512 +
                         h * 64 + kh * 32 + g * 8;
      qfh[qt][kh] = *reinterpret_cast<const v8s*>(&qhi[off]);
      qfl[qt][kh] = *reinterpret_cast<const v8s*>(&qlo[off]);
    }

  v4f ctx[2][4];
#pragma unroll
  for (int qt = 0; qt < 2; ++qt)
#pragma unroll
    for (int dt = 0; dt < 4; ++dt) ctx[qt][dt] = (v4f){0.f, 0.f, 0.f, 0.f};
  float mrun[2][4], lrun[2][4];
#pragma unroll
  for (int qt = 0; qt < 2; ++qt)
#pragma unroll
    for (int r = 0; r < 4; ++r) {
      mrun[qt][r] = -1.0e30f;
      lrun[qt][r] = 0.f;
    }

  const int srow = tid >> 3;  // 0..31
  const int sseg = tid & 7;   // 0..7

  uint4 sk0, sk1, sl0, sl1, sv0, sv1;
#define LOAD_TILE(KT)                                                          \
  {                                                                            \
    const size_t ka0 =                                                         \
        ((size_t)(b * 2048 + (KT) * 64 + srow)) * 512 + h * 64 + sseg * 8;     \
    const size_t ka1 = ka0 + (size_t)32 * 512;                                 \
    sk0 = *reinterpret_cast<const uint4*>(&khi[ka0]);                          \
    sk1 = *reinterpret_cast<const uint4*>(&khi[ka1]);                          \
    sl0 = *reinterpret_cast<const uint4*>(&klo[ka0]);                          \
    sl1 = *reinterpret_cast<const uint4*>(&klo[ka1]);                          \
    const size_t va0 =                                                         \
        ((size_t)(b * 512 + h * 64 + srow)) * 2048 + (KT) * 64 + sseg * 8;     \
    const size_t va1 = va0 + (size_t)32 * 2048;                                \
    sv0 = *reinterpret_cast<const uint4*>(&vt[va0]);                           \
    sv1 = *reinterpret_cast<const uint4*>(&vt[va1]);                           \
  }

  LOAD_TILE(0);  // prologue prefetch

  for (int kt = 0; kt < NT; ++kt) {
    __syncthreads();  // previous tile's LDS reads complete
    *reinterpret_cast<uint4*>(&Khs[srow][sseg * 8]) = sk0;
    *reinterpret_cast<uint4*>(&Khs[srow + 32][sseg * 8]) = sk1;
    *reinterpret_cast<uint4*>(&Kls[srow][sseg * 8]) = sl0;
    *reinterpret_cast<uint4*>(&Kls[srow + 32][sseg * 8]) = sl1;
    *reinterpret_cast<uint4*>(&Vts[srow][sseg * 8]) = sv0;
    *reinterpret_cast<uint4*>(&Vts[srow + 32][sseg * 8]) = sv1;
    __syncthreads();

    // issue NEXT tile's loads now: latency hides under compute below (T14)
    const int ktn = (kt < NT - 1) ? kt + 1 : kt;
    LOAD_TILE(ktn);

    // ---- QK^T: 3-term split, 48 MFMAs ----
    v4f s[2][4];
#pragma unroll
    for (int qt = 0; qt < 2; ++qt)
#pragma unroll
      for (int ct = 0; ct < 4; ++ct) s[qt][ct] = (v4f){0.f, 0.f, 0.f, 0.f};
#pragma unroll
    for (int kh = 0; kh < 2; ++kh)
#pragma unroll
      for (int ct = 0; ct < 4; ++ct) {
        const v8s bh =
            *reinterpret_cast<const v8s*>(&Khs[ct * 16 + c][kh * 32 + g * 8]);
        const v8s bl =
            *reinterpret_cast<const v8s*>(&Kls[ct * 16 + c][kh * 32 + g * 8]);
#pragma unroll
        for (int qt = 0; qt < 2; ++qt) {
          s[qt][ct] = MFMA16(qfh[qt][kh], bh, s[qt][ct]);
          s[qt][ct] = MFMA16(qfh[qt][kh], bl, s[qt][ct]);
          s[qt][ct] = MFMA16(qfl[qt][kh], bh, s[qt][ct]);
        }
      }

    // ---- online softmax (rows r = g*4+r across 16 c-lanes) ----
#pragma unroll
    for (int qt = 0; qt < 2; ++qt) {
      float al[4];
#pragma unroll
      for (int r = 0; r < 4; ++r) {
        float mx = fmaxf(fmaxf(s[qt][0][r], s[qt][1][r]),
                         fmaxf(s[qt][2][r], s[qt][3][r]));
        mx = fmaxf(mx, __shfl_xor(mx, 1, 16));
        mx = fmaxf(mx, __shfl_xor(mx, 2, 16));
        mx = fmaxf(mx, __shfl_xor(mx, 4, 16));
        mx = fmaxf(mx, __shfl_xor(mx, 8, 16));
        const float mn = fmaxf(mrun[qt][r], mx);
        al[r] = __expf(mrun[qt][r] - mn);
        mrun[qt][r] = mn;
      }
#pragma unroll
      for (int ct = 0; ct < 4; ++ct)
#pragma unroll
        for (int r = 0; r < 4; ++r)
          s[qt][ct][r] = __expf(s[qt][ct][r] - mrun[qt][r]);
#pragma unroll
      for (int r = 0; r < 4; ++r) {
        float ps = s[qt][0][r] + s[qt][1][r] + s[qt][2][r] + s[qt][3][r];
        ps += __shfl_xor(ps, 1, 16);
        ps += __shfl_xor(ps, 2, 16);
        ps += __shfl_xor(ps, 4, 16);
        ps += __shfl_xor(ps, 8, 16);
        lrun[qt][r] = lrun[qt][r] * al[r] + ps;
      }
#pragma unroll
      for (int dt = 0; dt < 4; ++dt)
#pragma unroll
        for (int r = 0; r < 4; ++r) ctx[qt][dt][r] *= al[r];

      // ---- pack P hi|lo into swizzled u32 plane (s[qt] dies here) ----
#pragma unroll
      for (int ct = 0; ct < 4; ++ct)
#pragma unroll
        for (int r = 0; r < 4; ++r) {
          const float p = s[qt][ct][r];
          const unsigned u = __float_as_uint(p);
          const unsigned hi = u >> 16;
          const float lof = p - __uint_as_float(u & 0xffff0000u);
          const unsigned lo = __float_as_uint(lof) >> 16;
          Pl[w][qt * 16 + g * 4 + r][(ct * 16 + c) ^ (g << 2)] = hi | (lo << 16);
        }
    }

    // ---- PV: single pass, hi+lo MFMAs (same-wave DS RAW, no barrier) ----
    const int cc4 = (c >> 2) << 2;  // swizzle key for reads (row = qt*16+c)
#pragma unroll
    for (int qt = 0; qt < 2; ++qt)
#pragma unroll
      for (int kh = 0; kh < 2; ++kh) {
        const uint4 a0 = *reinterpret_cast<const uint4*>(
            &Pl[w][qt * 16 + c][(kh * 32 + g * 8) ^ cc4]);
        const uint4 a1 = *reinterpret_cast<const uint4*>(
            &Pl[w][qt * 16 + c][(kh * 32 + g * 8 + 4) ^ cc4]);
        uint4 hh, ll;
        hh.x = (a0.x & 0xffffu) | (a0.y << 16);
        hh.y = (a0.z & 0xffffu) | (a0.w << 16);
        hh.z = (a1.x & 0xffffu) | (a1.y << 16);
        hh.w = (a1.z & 0xffffu) | (a1.w << 16);
        ll.x = (a0.x >> 16) | (a0.y & 0xffff0000u);
        ll.y = (a0.z >> 16) | (a0.w & 0xffff0000u);
        ll.z = (a1.x >> 16) | (a1.y & 0xffff0000u);
        ll.w = (a1.z >> 16) | (a1.w & 0xffff0000u);
        const v8s pah = __builtin_bit_cast(v8s, hh);
        const v8s pal = __builtin_bit_cast(v8s, ll);
#pragma unroll
        for (int dt = 0; dt < 4; ++dt) {
          const v8s vb =
              *reinterpret_cast<const v8s*>(&Vts[dt * 16 + c][kh * 32 + g * 8]);
          ctx[qt][dt] = MFMA16(pah, vb, ctx[qt][dt]);
          ctx[qt][dt] = MFMA16(pal, vb, ctx[qt][dt]);
        }
      }
  }

  // ---- epilogue: normalize and store fp32 ----
#pragma unroll
  for (int qt = 0; qt < 2; ++qt) {
    float inv[4];
#pragma unroll
    for (int r = 0; r < 4; ++r) inv[r] = 1.0f / lrun[qt][r];
#pragma unroll
    for (int dt = 0; dt < 4; ++dt)
#pragma unroll
      for (int r = 0; r < 4; ++r)
        out[((size_t)(b * 2048 + q0 + qt * 16 + g * 4 + r)) * 512 + h * 64 +
            dt * 16 + c] = ctx[qt][dt][r] * inv[r];
  }
}

extern "C" void kernel_launch(void* const* d_in, const int* in_sizes, int n_in,
                              void* d_out, int out_size, void* d_ws,
                              size_t ws_size, hipStream_t stream) {
  const float* q = (const float*)d_in[0];
  const float* k = (const float*)d_in[1];
  const float* v = (const float*)d_in[2];
  const float* Wq_w = (const float*)d_in[3];
  const float* Wq_b = (const float*)d_in[4];
  const float* Wk_w = (const float*)d_in[5];
  const float* Wk_b = (const float*)d_in[6];
  const float* Wv_w = (const float*)d_in[7];
  const float* Wv_b = (const float*)d_in[8];
  float* out = (float*)d_out;

  unsigned short* q_hi = (unsigned short*)d_ws;
  unsigned short* q_lo = q_hi + PLANE;
  unsigned short* k_hi = q_lo + PLANE;
  unsigned short* k_lo = k_hi + PLANE;
  unsigned short* v_b = k_lo + PLANE;
  unsigned short* vt = v_b + PLANE;  // 6 planes * 8 MiB = 48 MiB

  dim3 pgrid(ROWS / 64, D_MODEL / 256, 3);
  proj_mfma_kernel<<<pgrid, 256, 0, stream>>>(q, k, v, Wq_w, Wq_b, Wk_w, Wk_b,
                                              Wv_w, Wv_b, q_hi, q_lo, k_hi,
                                              k_lo, v_b);

  dim3 tgrid(SEQ / 64, D_MODEL / 64, BATCH);
  vtrans_kernel<<<tgrid, 256, 0, stream>>>(v_b, vt);

  dim3 agrid(BATCH * NUM_HEADS * (SEQ / 128));
  mha_attn_mfma<<<agrid, 256, 0, stream>>>(q_hi, q_lo, k_hi, k_lo, vt, out);
}